// Round 4
// baseline (1545.699 us; speedup 1.0000x reference)
//
#include <hip/hip_runtime.h>

#define DD    64
#define WCOLS 68   // D + EF
#define TILE  64   // dst nodes per block

__device__ __forceinline__ float lane_bcast(float v, int k) {
    return __int_as_float(__builtin_amdgcn_readlane(__float_as_int(v), k));
}

// ---------------------------------------------------------------------------
// CSR build: histogram of dst
// ---------------------------------------------------------------------------
__global__ __launch_bounds__(256) void hist_kernel(
    const int* __restrict__ dst, int* __restrict__ deg, int E)
{
    int i = blockIdx.x * 256 + threadIdx.x;
    int stride = gridDim.x * 256;
    for (; i < E; i += stride) atomicAdd(&deg[dst[i]], 1);
}

// scan phase 1: exclusive scan within 1024-element chunks (256 thr x 4 items)
__global__ __launch_bounds__(256) void scan1_kernel(
    const int* __restrict__ deg, int* __restrict__ rowp, int* __restrict__ bsum, int N)
{
    __shared__ int lds[256];
    int base = blockIdx.x * 1024;
    int t = threadIdx.x;
    int idx0 = base + t * 4;
    int v[4];
    #pragma unroll
    for (int j = 0; j < 4; ++j) v[j] = (idx0 + j < N) ? deg[idx0 + j] : 0;
    lds[t] = v[0] + v[1] + v[2] + v[3];
    __syncthreads();
    for (int off = 1; off < 256; off <<= 1) {
        int x = (t >= off) ? lds[t - off] : 0;
        __syncthreads();
        lds[t] += x;
        __syncthreads();
    }
    int run = (t > 0) ? lds[t - 1] : 0;
    if (t == 255) bsum[blockIdx.x] = lds[255];
    #pragma unroll
    for (int j = 0; j < 4; ++j) {
        if (idx0 + j < N) rowp[idx0 + j] = run;
        run += v[j];
    }
}

// scan phase 2: exclusive scan of chunk totals (nchunks <= 256)
__global__ __launch_bounds__(256) void scan2_kernel(int* __restrict__ bsum, int nchunks)
{
    __shared__ int lds[256];
    int t = threadIdx.x;
    int v = (t < nchunks) ? bsum[t] : 0;
    lds[t] = v;
    __syncthreads();
    for (int off = 1; off < 256; off <<= 1) {
        int x = (t >= off) ? lds[t - off] : 0;
        __syncthreads();
        lds[t] += x;
        __syncthreads();
    }
    if (t < nchunks) bsum[t] = (t > 0) ? lds[t - 1] : 0;
}

// scan phase 3: add chunk offsets; init cursor; rowp[N] = E
__global__ __launch_bounds__(256) void scan3_kernel(
    int* __restrict__ rowp, const int* __restrict__ bsum, int* __restrict__ cursor,
    int N, int E)
{
    int i = blockIdx.x * 256 + threadIdx.x;
    if (i == 0) rowp[N] = E;
    if (i < N) {
        int v = rowp[i] + bsum[i >> 10];
        rowp[i] = v;
        cursor[i] = v;
    }
}

// CSR fill: permute src + edge_attr into dst-grouped order; also local dst byte
__global__ __launch_bounds__(256) void fill_kernel(
    const int* __restrict__ src, const int* __restrict__ dst,
    const float* __restrict__ eattr, int* __restrict__ cursor,
    int* __restrict__ srcp, float4* __restrict__ eap,
    unsigned char* __restrict__ dstp8, int E)
{
    int i = blockIdx.x * 256 + threadIdx.x;
    int stride = gridDim.x * 256;
    for (; i < E; i += stride) {
        int d = dst[i];
        int pos = atomicAdd(&cursor[d], 1);
        srcp[pos]  = src[i];
        eap[pos]   = *(const float4*)(eattr + (size_t)i * 4);
        dstp8[pos] = (unsigned char)(d & (TILE - 1));
    }
}

// ---------------------------------------------------------------------------
// init: x = emb[x_ids];  Y = x @ W1a.T + b1
// ---------------------------------------------------------------------------
__global__ __launch_bounds__(256) void init_kernel(
    const int* __restrict__ x_ids, const float* __restrict__ emb,
    const float* __restrict__ W1, const float* __restrict__ b1,
    float* __restrict__ x0, float* __restrict__ Y, int N)
{
    __shared__ float WaT[64 * 64];              // WaT[k*64+d] = W1[d][k]
    for (int i = threadIdx.x; i < 64 * 64; i += 256) {
        int d = i & 63, k = i >> 6;
        WaT[i] = W1[d * WCOLS + k];
    }
    __syncthreads();

    int lane = threadIdx.x & 63;
    int wid  = (blockIdx.x * 256 + threadIdx.x) >> 6;
    int nw   = (gridDim.x * 256) >> 6;
    float bias = b1[lane];

    for (int base = wid * 4; base < N; base += nw * 4) {
        int nvalid = N - base; if (nvalid > 4) nvalid = 4;
        float xv[4], acc[4];
        #pragma unroll
        for (int j = 0; j < 4; ++j) {
            xv[j] = (j < nvalid) ? emb[x_ids[base + j] * DD + lane] : 0.f;
            acc[j] = bias;
        }
        #pragma unroll 8
        for (int k = 0; k < 64; ++k) {
            float w = WaT[k * 64 + lane];
            #pragma unroll
            for (int j = 0; j < 4; ++j)
                acc[j] = fmaf(w, lane_bcast(xv[j], k), acc[j]);
        }
        #pragma unroll
        for (int j = 0; j < 4; ++j) {
            if (j < nvalid) {
                size_t o = (size_t)(base + j) * DD + lane;
                x0[o] = xv[j];
                Y[o]  = acc[j];
            }
        }
    }
}

// ---------------------------------------------------------------------------
// tile round: block owns TILE consecutive dst nodes.
//  phase 1: 4 waves split the contiguous edge range edge-parallel;
//           agg[t][lane] += relu(Y[src]+We·ea) via LDS float atomics
//  phase 2: node update from LDS agg, 4-node register blocking
// ---------------------------------------------------------------------------
template<bool FUSE_Y, bool FINAL>
__global__ __launch_bounds__(256) void tile_kernel(
    const int* __restrict__ rowp, const int* __restrict__ srcp,
    const float4* __restrict__ eap, const unsigned char* __restrict__ dstp8,
    const float* __restrict__ Y_in, const float* __restrict__ Wm,
    const float* __restrict__ Wu, const float* __restrict__ bu,
    const float* __restrict__ Wn, const float* __restrict__ bn,
    float* __restrict__ x_io, float* __restrict__ Y_out,
    float* __restrict__ out_mean, int N, float inv_n)
{
    __shared__ float agg[TILE * 64];            // 16 KB
    __shared__ float WuT[64 * 64];              // 16 KB, WuT[k*64+d]
    __shared__ float WnT[FUSE_Y ? 64 * 64 : 1];
    __shared__ float red[FINAL ? 256 : 1];

    for (int i = threadIdx.x; i < 64 * 64; i += 256) {
        int d = i & 63, k = i >> 6;
        agg[i] = 0.f;
        WuT[i] = Wu[d * DD + k];
        if (FUSE_Y) WnT[i] = Wn[d * WCOLS + k];
    }
    __syncthreads();

    int lane = threadIdx.x & 63;
    int wv   = __builtin_amdgcn_readfirstlane(threadIdx.x >> 6);
    float w0 = Wm[lane * WCOLS + 64];
    float w1 = Wm[lane * WCOLS + 65];
    float w2 = Wm[lane * WCOLS + 66];
    float w3 = Wm[lane * WCOLS + 67];

    int base = blockIdx.x * TILE;
    int nend = base + TILE; if (nend > N) nend = N;
    int beg = rowp[base], end = rowp[nend];

    // ---- phase 1: edge-parallel gather ----
    int T   = end - beg;
    int per = (T + 3) >> 2;
    int e0  = beg + wv * per;
    int e1  = e0 + per; if (e1 > end) e1 = end;

    int e = e0;
    for (; e + 7 < e1; e += 8) {
        int s[8]; float4 a[8]; int t8[8];
        #pragma unroll
        for (int j = 0; j < 8; ++j) {
            s[j]  = srcp[e + j];
            a[j]  = eap[e + j];
            t8[j] = dstp8[e + j];
        }
        float y[8];
        #pragma unroll
        for (int j = 0; j < 8; ++j)
            y[j] = Y_in[(size_t)s[j] * DD + lane];
        #pragma unroll
        for (int j = 0; j < 8; ++j) {
            float m = fmaf(w0, a[j].x, y[j]);
            m = fmaf(w1, a[j].y, m);
            m = fmaf(w2, a[j].z, m);
            m = fmaf(w3, a[j].w, m);
            m = fmaxf(m, 0.f);
            atomicAdd(&agg[t8[j] * 64 + lane], m);
        }
    }
    for (; e < e1; ++e) {
        int s0 = srcp[e];
        float4 a0 = eap[e];
        int t0 = dstp8[e];
        float m = fmaf(w0, a0.x, Y_in[(size_t)s0 * DD + lane]);
        m = fmaf(w1, a0.y, m);
        m = fmaf(w2, a0.z, m);
        m = fmaf(w3, a0.w, m);
        atomicAdd(&agg[t0 * 64 + lane], fmaxf(m, 0.f));
    }
    __syncthreads();

    // ---- phase 2: node update, 4-node register blocking ----
    float biasu = bu[lane];
    float biasn = FUSE_Y ? bn[lane] : 0.f;
    float lsum = 0.f;

    #pragma unroll
    for (int g = 0; g < 4; ++g) {
        int t0 = wv * 16 + g * 4;               // local node base (0..60)
        int n0 = base + t0;
        int nv = N - n0; if (nv > 4) nv = 4; if (nv < 0) nv = 0;

        float v[4], acc[4];
        #pragma unroll
        for (int j = 0; j < 4; ++j) {
            v[j] = (j < nv)
                 ? x_io[(size_t)(n0 + j) * DD + lane] + agg[(t0 + j) * 64 + lane]
                 : 0.f;
            acc[j] = biasu;
        }
        #pragma unroll 8
        for (int k = 0; k < 64; ++k) {
            float w = WuT[k * 64 + lane];
            #pragma unroll
            for (int j = 0; j < 4; ++j)
                acc[j] = fmaf(w, lane_bcast(v[j], k), acc[j]);
        }
        float o4[4];
        #pragma unroll
        for (int j = 0; j < 4; ++j) o4[j] = fmaxf(acc[j], 0.f);

        if (FUSE_Y) {
            float acc2[4];
            #pragma unroll
            for (int j = 0; j < 4; ++j) acc2[j] = biasn;
            #pragma unroll 8
            for (int k = 0; k < 64; ++k) {
                float w = WnT[k * 64 + lane];
                #pragma unroll
                for (int j = 0; j < 4; ++j)
                    acc2[j] = fmaf(w, lane_bcast(o4[j], k), acc2[j]);
            }
            #pragma unroll
            for (int j = 0; j < 4; ++j) {
                if (j < nv) {
                    size_t o = (size_t)(n0 + j) * DD + lane;
                    x_io[o]  = o4[j];
                    Y_out[o] = acc2[j];
                }
            }
        }
        if (FINAL) {
            #pragma unroll
            for (int j = 0; j < 4; ++j)
                if (j < nv) lsum += o4[j];
        }
    }

    if (FINAL) {
        red[threadIdx.x] = lsum;
        __syncthreads();
        if (threadIdx.x < 64) {
            float s = red[threadIdx.x] + red[threadIdx.x + 64] +
                      red[threadIdx.x + 128] + red[threadIdx.x + 192];
            unsafeAtomicAdd(&out_mean[threadIdx.x], s * inv_n);
        }
    }
}

// ---------------------------------------------------------------------------
extern "C" void kernel_launch(void* const* d_in, const int* in_sizes, int n_in,
                              void* d_out, int out_size, void* d_ws, size_t ws_size,
                              hipStream_t stream) {
    const int*   x_ids = (const int*)d_in[0];
    const int*   ei    = (const int*)d_in[1];
    const float* eattr = (const float*)d_in[2];
    const float* emb   = (const float*)d_in[3];
    const float* W1    = (const float*)d_in[4];
    const float* b1    = (const float*)d_in[5];
    const float* Wu1   = (const float*)d_in[6];
    const float* bu1   = (const float*)d_in[7];
    const float* W2    = (const float*)d_in[8];
    const float* b2    = (const float*)d_in[9];
    const float* Wu2   = (const float*)d_in[10];
    const float* bu2   = (const float*)d_in[11];

    const int N = in_sizes[0];
    const int E = in_sizes[1] / 2;
    const int* src = ei;
    const int* dst = ei + E;

    float* ws = (float*)d_ws;
    size_t stride = (size_t)N * DD;
    float*  x    = ws;                       // N*64
    float*  Ya   = ws + stride;              // N*64
    float*  Yb   = ws + 2 * stride;          // N*64
    float*  eapf = ws + 3 * stride;          // E*4 (16B-aligned)
    int*    srcp = (int*)(eapf + (size_t)E * 4);   // E
    int*    rowp = srcp + E;                 // N+1
    int*    deg  = rowp + N + 1;             // N
    int*    cur  = deg + N;                  // N
    int*    bsum = cur + N;                  // 256
    unsigned char* dstp8 = (unsigned char*)(bsum + 256);  // E bytes
    float4* eap  = (float4*)eapf;

    float* out = (float*)d_out;
    float inv_n = 1.0f / (float)N;
    int nchunks = (N + 1023) / 1024;
    int ntiles  = (N + TILE - 1) / TILE;

    hipMemsetAsync(deg, 0, (size_t)N * sizeof(int), stream);
    hipMemsetAsync(out, 0, DD * sizeof(float), stream);

    // CSR build
    hist_kernel <<<2048, 256, 0, stream>>>(dst, deg, E);
    scan1_kernel<<<nchunks, 256, 0, stream>>>(deg, rowp, bsum, N);
    scan2_kernel<<<1, 256, 0, stream>>>(bsum, nchunks);
    scan3_kernel<<<(N + 255) / 256, 256, 0, stream>>>(rowp, bsum, cur, N, E);
    fill_kernel <<<2048, 256, 0, stream>>>(src, dst, eattr, cur, srcp, eap, dstp8, E);

    // x = emb[x_ids]; Ya = x @ W1a.T + b1
    init_kernel<<<1024, 256, 0, stream>>>(x_ids, emb, W1, b1, x, Ya, N);

    // round 1 (writes x in place, Yb for round 2)
    tile_kernel<true, false><<<ntiles, 256, 0, stream>>>(
        rowp, srcp, eap, dstp8, Ya, W1, Wu1, bu1, W2, b2, x, Yb, nullptr, N, inv_n);
    // round 2 (final mean)
    tile_kernel<false, true><<<ntiles, 256, 0, stream>>>(
        rowp, srcp, eap, dstp8, Yb, W2, Wu2, bu2, nullptr, nullptr, x, nullptr, out, N, inv_n);
}

// Round 12
// 607.195 us; speedup vs baseline: 2.5456x; 2.5456x over previous
//
#include <hip/hip_runtime.h>

#define DD    64
#define WCOLS 68   // D + EF
#define VV    100  // vocab size

__device__ __forceinline__ float lane_bcast(float v, int k) {
    return __int_as_float(__builtin_amdgcn_readlane(__float_as_int(v), k));
}

// ---------------------------------------------------------------------------
// CSR build: histogram of dst
// ---------------------------------------------------------------------------
__global__ __launch_bounds__(256) void hist_kernel(
    const int* __restrict__ dst, int* __restrict__ deg, int E)
{
    int i = blockIdx.x * 256 + threadIdx.x;
    int stride = gridDim.x * 256;
    for (; i < E; i += stride) atomicAdd(&deg[dst[i]], 1);
}

// scan phase 1: exclusive scan within 1024-element chunks (256 thr x 4 items)
__global__ __launch_bounds__(256) void scan1_kernel(
    const int* __restrict__ deg, int* __restrict__ rowp, int* __restrict__ bsum, int N)
{
    __shared__ int lds[256];
    int base = blockIdx.x * 1024;
    int t = threadIdx.x;
    int idx0 = base + t * 4;
    int v[4];
    #pragma unroll
    for (int j = 0; j < 4; ++j) v[j] = (idx0 + j < N) ? deg[idx0 + j] : 0;
    lds[t] = v[0] + v[1] + v[2] + v[3];
    __syncthreads();
    for (int off = 1; off < 256; off <<= 1) {
        int x = (t >= off) ? lds[t - off] : 0;
        __syncthreads();
        lds[t] += x;
        __syncthreads();
    }
    int run = (t > 0) ? lds[t - 1] : 0;
    if (t == 255) bsum[blockIdx.x] = lds[255];
    #pragma unroll
    for (int j = 0; j < 4; ++j) {
        if (idx0 + j < N) rowp[idx0 + j] = run;
        run += v[j];
    }
}

// scan phase 2: exclusive scan of chunk totals (nchunks <= 256)
__global__ __launch_bounds__(256) void scan2_kernel(int* __restrict__ bsum, int nchunks)
{
    __shared__ int lds[256];
    int t = threadIdx.x;
    int v = (t < nchunks) ? bsum[t] : 0;
    lds[t] = v;
    __syncthreads();
    for (int off = 1; off < 256; off <<= 1) {
        int x = (t >= off) ? lds[t - off] : 0;
        __syncthreads();
        lds[t] += x;
        __syncthreads();
    }
    if (t < nchunks) bsum[t] = (t > 0) ? lds[t - 1] : 0;
}

// scan phase 3: add chunk offsets; init cursor; rowp[N] = E
__global__ __launch_bounds__(256) void scan3_kernel(
    int* __restrict__ rowp, const int* __restrict__ bsum, int* __restrict__ cursor,
    int N, int E)
{
    int i = blockIdx.x * 256 + threadIdx.x;
    if (i == 0) rowp[N] = E;
    if (i < N) {
        int v = rowp[i] + bsum[i >> 10];
        rowp[i] = v;
        cursor[i] = v;
    }
}

// CSR fill: permute src + edge_attr into dst-grouped order; vocab id of src
__global__ __launch_bounds__(256) void fill_kernel(
    const int* __restrict__ src, const int* __restrict__ dst,
    const int* __restrict__ x_ids, const float* __restrict__ eattr,
    int* __restrict__ cursor,
    int* __restrict__ srcp, unsigned char* __restrict__ vb,
    float4* __restrict__ eap, int E)
{
    int i = blockIdx.x * 256 + threadIdx.x;
    int stride = gridDim.x * 256;
    for (; i < E; i += stride) {
        int s = src[i];
        int d = dst[i];
        int pos = atomicAdd(&cursor[d], 1);
        srcp[pos] = s;
        vb[pos]   = (unsigned char)x_ids[s];
        eap[pos]  = *(const float4*)(eattr + (size_t)i * 4);
    }
}

// ---------------------------------------------------------------------------
// vocab precompute: YV[v] = emb[v] @ W1a.T + b1   (100 rows)
// ---------------------------------------------------------------------------
__global__ __launch_bounds__(256) void vocab_kernel(
    const float* __restrict__ emb, const float* __restrict__ W1,
    const float* __restrict__ b1, float* __restrict__ YV)
{
    __shared__ float WaT[64 * 64];              // WaT[k*64+d] = W1[d][k]
    for (int i = threadIdx.x; i < 64 * 64; i += 256) {
        int d = i & 63, k = i >> 6;
        WaT[i] = W1[d * WCOLS + k];
    }
    __syncthreads();

    int lane = threadIdx.x & 63;
    int wv = blockIdx.x * 4 + (threadIdx.x >> 6);
    if (wv >= VV) return;
    float xv = emb[wv * DD + lane];
    float acc = b1[lane];
    #pragma unroll 8
    for (int k = 0; k < 64; ++k)
        acc = fmaf(WaT[k * 64 + lane], lane_bcast(xv, k), acc);
    YV[wv * DD + lane] = acc;
}

// ---------------------------------------------------------------------------
// round 1 (fused, no global gather): per dst node (one wave each):
//   acc = sum_e relu(YVs[vb(e)] + We1·ea(e))     (LDS vocab table!)
//   o   = relu((emb[x_ids[n]] + acc) @ Wu1.T + bu1)
//   x1 = o;  Yb = o @ W2a.T + b2
// ---------------------------------------------------------------------------
__global__ __launch_bounds__(256) void round1_kernel(
    const int* __restrict__ rowp, const unsigned char* __restrict__ vb,
    const float4* __restrict__ eap, const float* __restrict__ YV,
    const int* __restrict__ x_ids, const float* __restrict__ emb,
    const float* __restrict__ W1,
    const float* __restrict__ Wu, const float* __restrict__ bu,
    const float* __restrict__ Wn, const float* __restrict__ bn,
    float* __restrict__ x1, float* __restrict__ Yb, int N)
{
    __shared__ float YVs[VV * 64];              // 25.6 KB
    __shared__ float WuT[64 * 64];              // 16 KB  WuT[k*64+d]
    __shared__ float WnT[64 * 64];              // 16 KB
    for (int i = threadIdx.x; i < VV * 64; i += 256) YVs[i] = YV[i];
    for (int i = threadIdx.x; i < 64 * 64; i += 256) {
        int d = i & 63, k = i >> 6;
        WuT[i] = Wu[d * DD + k];
        WnT[i] = Wn[d * WCOLS + k];
    }
    __syncthreads();

    int lane = threadIdx.x & 63;
    int wid  = __builtin_amdgcn_readfirstlane((blockIdx.x * 256 + (int)threadIdx.x) >> 6);
    int nw   = (gridDim.x * 256) >> 6;
    float w0 = W1[lane * WCOLS + 64];
    float w1 = W1[lane * WCOLS + 65];
    float w2 = W1[lane * WCOLS + 66];
    float w3 = W1[lane * WCOLS + 67];
    float biasu = bu[lane];
    float biasn = bn[lane];

    for (int n = wid; n < N; n += nw) {
        int beg = rowp[n], end = rowp[n + 1];
        float acc = 0.f;
        int e = beg;
        for (; e + 3 < end; e += 4) {
            int v0 = vb[e], v1 = vb[e + 1], v2 = vb[e + 2], v3 = vb[e + 3];
            float4 a0 = eap[e], a1 = eap[e + 1], a2 = eap[e + 2], a3 = eap[e + 3];
            float y0 = YVs[v0 * 64 + lane];
            float y1 = YVs[v1 * 64 + lane];
            float y2 = YVs[v2 * 64 + lane];
            float y3 = YVs[v3 * 64 + lane];
            float m0 = y0 + w0 * a0.x + w1 * a0.y + w2 * a0.z + w3 * a0.w;
            float m1 = y1 + w0 * a1.x + w1 * a1.y + w2 * a1.z + w3 * a1.w;
            float m2 = y2 + w0 * a2.x + w1 * a2.y + w2 * a2.z + w3 * a2.w;
            float m3 = y3 + w0 * a3.x + w1 * a3.y + w2 * a3.z + w3 * a3.w;
            acc += fmaxf(m0, 0.f) + fmaxf(m1, 0.f) + fmaxf(m2, 0.f) + fmaxf(m3, 0.f);
        }
        for (; e < end; ++e) {
            int v0 = vb[e];
            float4 a0 = eap[e];
            float y0 = YVs[v0 * 64 + lane];
            float m0 = y0 + w0 * a0.x + w1 * a0.y + w2 * a0.z + w3 * a0.w;
            acc += fmaxf(m0, 0.f);
        }

        int id = x_ids[n];
        float v = emb[(size_t)id * DD + lane] + acc;
        float au = biasu;
        #pragma unroll 8
        for (int k = 0; k < 64; ++k)
            au = fmaf(WuT[k * 64 + lane], lane_bcast(v, k), au);
        float oo = fmaxf(au, 0.f);

        float an = biasn;
        #pragma unroll 8
        for (int k = 0; k < 64; ++k)
            an = fmaf(WnT[k * 64 + lane], lane_bcast(oo, k), an);

        size_t o = (size_t)n * DD + lane;
        x1[o] = oo;
        Yb[o] = an;
    }
}

// ---------------------------------------------------------------------------
// round 2 (final): per dst node:
//   acc = sum_e relu(Yb[src(e)] + We2·ea(e))     (global gather, as r3)
//   o   = relu((x1 + acc) @ Wu2.T + bu2);  out_mean += o / N
// ---------------------------------------------------------------------------
__global__ __launch_bounds__(256) void round2_kernel(
    const int* __restrict__ rowp, const int* __restrict__ srcp,
    const float4* __restrict__ eap, const float* __restrict__ Y_in,
    const float* __restrict__ Wm,
    const float* __restrict__ Wu, const float* __restrict__ bu,
    const float* __restrict__ x1, float* __restrict__ out_mean,
    int N, float inv_n)
{
    __shared__ float WuT[64 * 64];
    __shared__ float red[256];
    for (int i = threadIdx.x; i < 64 * 64; i += 256) {
        int d = i & 63, k = i >> 6;
        WuT[i] = Wu[d * DD + k];
    }
    __syncthreads();

    int lane = threadIdx.x & 63;
    int wid  = __builtin_amdgcn_readfirstlane((blockIdx.x * 256 + (int)threadIdx.x) >> 6);
    int nw   = (gridDim.x * 256) >> 6;
    float w0 = Wm[lane * WCOLS + 64];
    float w1 = Wm[lane * WCOLS + 65];
    float w2 = Wm[lane * WCOLS + 66];
    float w3 = Wm[lane * WCOLS + 67];
    float biasu = bu[lane];
    float lsum = 0.f;

    for (int n = wid; n < N; n += nw) {
        int beg = rowp[n], end = rowp[n + 1];
        float acc = 0.f;
        int e = beg;
        for (; e + 3 < end; e += 4) {
            int s0 = srcp[e], s1 = srcp[e + 1], s2 = srcp[e + 2], s3 = srcp[e + 3];
            float4 a0 = eap[e], a1 = eap[e + 1], a2 = eap[e + 2], a3 = eap[e + 3];
            float y0 = Y_in[(size_t)s0 * DD + lane];
            float y1 = Y_in[(size_t)s1 * DD + lane];
            float y2 = Y_in[(size_t)s2 * DD + lane];
            float y3 = Y_in[(size_t)s3 * DD + lane];
            float m0 = y0 + w0 * a0.x + w1 * a0.y + w2 * a0.z + w3 * a0.w;
            float m1 = y1 + w0 * a1.x + w1 * a1.y + w2 * a1.z + w3 * a1.w;
            float m2 = y2 + w0 * a2.x + w1 * a2.y + w2 * a2.z + w3 * a2.w;
            float m3 = y3 + w0 * a3.x + w1 * a3.y + w2 * a3.z + w3 * a3.w;
            acc += fmaxf(m0, 0.f) + fmaxf(m1, 0.f) + fmaxf(m2, 0.f) + fmaxf(m3, 0.f);
        }
        for (; e < end; ++e) {
            int s0 = srcp[e];
            float4 a0 = eap[e];
            float y0 = Y_in[(size_t)s0 * DD + lane];
            float m0 = y0 + w0 * a0.x + w1 * a0.y + w2 * a0.z + w3 * a0.w;
            acc += fmaxf(m0, 0.f);
        }

        size_t o = (size_t)n * DD + lane;
        float v = x1[o] + acc;
        float au = biasu;
        #pragma unroll 8
        for (int k = 0; k < 64; ++k)
            au = fmaf(WuT[k * 64 + lane], lane_bcast(v, k), au);
        lsum += fmaxf(au, 0.f);
    }

    red[threadIdx.x] = lsum;
    __syncthreads();
    if (threadIdx.x < 64) {
        float s = red[threadIdx.x] + red[threadIdx.x + 64] +
                  red[threadIdx.x + 128] + red[threadIdx.x + 192];
        unsafeAtomicAdd(&out_mean[threadIdx.x], s * inv_n);
    }
}

// ---------------------------------------------------------------------------
extern "C" void kernel_launch(void* const* d_in, const int* in_sizes, int n_in,
                              void* d_out, int out_size, void* d_ws, size_t ws_size,
                              hipStream_t stream) {
    const int*   x_ids = (const int*)d_in[0];
    const int*   ei    = (const int*)d_in[1];
    const float* eattr = (const float*)d_in[2];
    const float* emb   = (const float*)d_in[3];
    const float* W1    = (const float*)d_in[4];
    const float* b1    = (const float*)d_in[5];
    const float* Wu1   = (const float*)d_in[6];
    const float* bu1   = (const float*)d_in[7];
    const float* W2    = (const float*)d_in[8];
    const float* b2    = (const float*)d_in[9];
    const float* Wu2   = (const float*)d_in[10];
    const float* bu2   = (const float*)d_in[11];

    const int N = in_sizes[0];
    const int E = in_sizes[1] / 2;
    const int* src = ei;
    const int* dst = ei + E;

    float* ws = (float*)d_ws;
    size_t stride = (size_t)N * DD;
    float*  x1   = ws;                              // N*64
    float*  Yb   = ws + stride;                     // N*64
    float*  eapf = ws + 2 * stride;                 // E*4 (16B-aligned)
    int*    srcp = (int*)(eapf + (size_t)E * 4);    // E
    int*    rowp = srcp + E;                        // N+1
    int*    deg  = rowp + N + 1;                    // N
    int*    cur  = deg + N;                         // N
    int*    bsum = cur + N;                         // 256
    float*  YV   = (float*)(bsum + 256);            // 100*64
    unsigned char* vb = (unsigned char*)(YV + VV * 64);  // E bytes
    float4* eap  = (float4*)eapf;

    float* out = (float*)d_out;
    float inv_n = 1.0f / (float)N;
    int nchunks = (N + 1023) / 1024;

    hipMemsetAsync(deg, 0, (size_t)N * sizeof(int), stream);
    hipMemsetAsync(out, 0, DD * sizeof(float), stream);

    // CSR build
    hist_kernel <<<2048, 256, 0, stream>>>(dst, deg, E);
    scan1_kernel<<<nchunks, 256, 0, stream>>>(deg, rowp, bsum, N);
    scan2_kernel<<<1, 256, 0, stream>>>(bsum, nchunks);
    scan3_kernel<<<(N + 255) / 256, 256, 0, stream>>>(rowp, bsum, cur, N, E);
    fill_kernel <<<2048, 256, 0, stream>>>(src, dst, x_ids, eattr, cur, srcp, vb, eap, E);

    // vocab table: YV = emb @ W1a.T + b1
    vocab_kernel<<<(VV + 3) / 4, 256, 0, stream>>>(emb, W1, b1, YV);

    // round 1 (LDS vocab table, no gather) -> x1, Yb
    round1_kernel<<<2048, 256, 0, stream>>>(
        rowp, vb, eap, YV, x_ids, emb, W1, Wu1, bu1, W2, b2, x1, Yb, N);
    // round 2 (gather Yb) -> out mean
    round2_kernel<<<2048, 256, 0, stream>>>(
        rowp, srcp, eap, Yb, W2, Wu2, bu2, x1, out, N, inv_n);
}

// Round 13
// 596.871 us; speedup vs baseline: 2.5897x; 1.0173x over previous
//
#include <hip/hip_runtime.h>

#define DD    64
#define WCOLS 68   // D + EF
#define VV    100  // vocab size

__device__ __forceinline__ float lane_bcast(float v, int k) {
    return __int_as_float(__builtin_amdgcn_readlane(__float_as_int(v), k));
}

// ---------------------------------------------------------------------------
// CSR build: histogram of dst
// ---------------------------------------------------------------------------
__global__ __launch_bounds__(256) void hist_kernel(
    const int* __restrict__ dst, int* __restrict__ deg, int E)
{
    int i = blockIdx.x * 256 + threadIdx.x;
    int stride = gridDim.x * 256;
    for (; i < E; i += stride) atomicAdd(&deg[dst[i]], 1);
}

// scan phase 1: exclusive scan within 1024-element chunks (256 thr x 4 items)
__global__ __launch_bounds__(256) void scan1_kernel(
    const int* __restrict__ deg, int* __restrict__ rowp, int* __restrict__ bsum, int N)
{
    __shared__ int lds[256];
    int base = blockIdx.x * 1024;
    int t = threadIdx.x;
    int idx0 = base + t * 4;
    int v[4];
    #pragma unroll
    for (int j = 0; j < 4; ++j) v[j] = (idx0 + j < N) ? deg[idx0 + j] : 0;
    lds[t] = v[0] + v[1] + v[2] + v[3];
    __syncthreads();
    for (int off = 1; off < 256; off <<= 1) {
        int x = (t >= off) ? lds[t - off] : 0;
        __syncthreads();
        lds[t] += x;
        __syncthreads();
    }
    int run = (t > 0) ? lds[t - 1] : 0;
    if (t == 255) bsum[blockIdx.x] = lds[255];
    #pragma unroll
    for (int j = 0; j < 4; ++j) {
        if (idx0 + j < N) rowp[idx0 + j] = run;
        run += v[j];
    }
}

// scan phase 2: exclusive scan of chunk totals (nchunks <= 256)
__global__ __launch_bounds__(256) void scan2_kernel(int* __restrict__ bsum, int nchunks)
{
    __shared__ int lds[256];
    int t = threadIdx.x;
    int v = (t < nchunks) ? bsum[t] : 0;
    lds[t] = v;
    __syncthreads();
    for (int off = 1; off < 256; off <<= 1) {
        int x = (t >= off) ? lds[t - off] : 0;
        __syncthreads();
        lds[t] += x;
        __syncthreads();
    }
    if (t < nchunks) bsum[t] = (t > 0) ? lds[t - 1] : 0;
}

// scan phase 3: add chunk offsets; init cursor; rowp[N] = E
__global__ __launch_bounds__(256) void scan3_kernel(
    int* __restrict__ rowp, const int* __restrict__ bsum, int* __restrict__ cursor,
    int N, int E)
{
    int i = blockIdx.x * 256 + threadIdx.x;
    if (i == 0) rowp[N] = E;
    if (i < N) {
        int v = rowp[i] + bsum[i >> 10];
        rowp[i] = v;
        cursor[i] = v;
    }
}

// CSR fill: permute src + edge_attr into dst-grouped order; vocab id of src
__global__ __launch_bounds__(256) void fill_kernel(
    const int* __restrict__ src, const int* __restrict__ dst,
    const int* __restrict__ x_ids, const float* __restrict__ eattr,
    int* __restrict__ cursor,
    int* __restrict__ srcp, unsigned char* __restrict__ vb,
    float4* __restrict__ eap, int E)
{
    int i = blockIdx.x * 256 + threadIdx.x;
    int stride = gridDim.x * 256;
    for (; i < E; i += stride) {
        int s = src[i];
        int d = dst[i];
        int pos = atomicAdd(&cursor[d], 1);
        srcp[pos] = s;
        vb[pos]   = (unsigned char)x_ids[s];
        eap[pos]  = *(const float4*)(eattr + (size_t)i * 4);
    }
}

// ---------------------------------------------------------------------------
// vocab precompute: YV[v] = emb[v] @ W1a.T + b1   (100 rows)
// ---------------------------------------------------------------------------
__global__ __launch_bounds__(256) void vocab_kernel(
    const float* __restrict__ emb, const float* __restrict__ W1,
    const float* __restrict__ b1, float* __restrict__ YV)
{
    __shared__ float WaT[64 * 64];              // WaT[k*64+d] = W1[d][k]
    for (int i = threadIdx.x; i < 64 * 64; i += 256) {
        int d = i & 63, k = i >> 6;
        WaT[i] = W1[d * WCOLS + k];
    }
    __syncthreads();

    int lane = threadIdx.x & 63;
    int wv = blockIdx.x * 4 + (threadIdx.x >> 6);
    if (wv >= VV) return;
    float xv = emb[wv * DD + lane];
    float acc = b1[lane];
    #pragma unroll 8
    for (int k = 0; k < 64; ++k)
        acc = fmaf(WaT[k * 64 + lane], lane_bcast(xv, k), acc);
    YV[wv * DD + lane] = acc;
}

// ---------------------------------------------------------------------------
// round 1 (fused, no global gather, no WnT): per dst node (one wave each):
//   acc = sum_e relu(YVs[vb(e)] + We1·ea(e))     (LDS vocab table)
//   x1  = relu((emb[x_ids[n]] + acc) @ Wu1.T + bu1)
// LDS = YVs 25.6K + WuT 16K = 41.6 KB -> 3 blocks/CU (was 2 at 57.6 KB)
// ---------------------------------------------------------------------------
__global__ __launch_bounds__(256) void round1_kernel(
    const int* __restrict__ rowp, const unsigned char* __restrict__ vb,
    const float4* __restrict__ eap, const float* __restrict__ YV,
    const int* __restrict__ x_ids, const float* __restrict__ emb,
    const float* __restrict__ W1,
    const float* __restrict__ Wu, const float* __restrict__ bu,
    float* __restrict__ x1, int N)
{
    __shared__ float YVs[VV * 64];              // 25.6 KB
    __shared__ float WuT[64 * 64];              // 16 KB  WuT[k*64+d]
    for (int i = threadIdx.x; i < VV * 64; i += 256) YVs[i] = YV[i];
    for (int i = threadIdx.x; i < 64 * 64; i += 256) {
        int d = i & 63, k = i >> 6;
        WuT[i] = Wu[d * DD + k];
    }
    __syncthreads();

    int lane = threadIdx.x & 63;
    int wid  = __builtin_amdgcn_readfirstlane((blockIdx.x * 256 + (int)threadIdx.x) >> 6);
    int nw   = (gridDim.x * 256) >> 6;
    float w0 = W1[lane * WCOLS + 64];
    float w1 = W1[lane * WCOLS + 65];
    float w2 = W1[lane * WCOLS + 66];
    float w3 = W1[lane * WCOLS + 67];
    float biasu = bu[lane];

    for (int n = wid; n < N; n += nw) {
        int beg = rowp[n], end = rowp[n + 1];
        float acc = 0.f;
        int e = beg;
        // 8-deep unroll: more independent vb/eap/LDS loads in flight
        for (; e + 7 < end; e += 8) {
            int   v8[8]; float4 a8[8];
            #pragma unroll
            for (int j = 0; j < 8; ++j) { v8[j] = vb[e + j]; a8[j] = eap[e + j]; }
            float y8[8];
            #pragma unroll
            for (int j = 0; j < 8; ++j) y8[j] = YVs[v8[j] * 64 + lane];
            #pragma unroll
            for (int j = 0; j < 8; ++j) {
                float m = fmaf(w0, a8[j].x, y8[j]);
                m = fmaf(w1, a8[j].y, m);
                m = fmaf(w2, a8[j].z, m);
                m = fmaf(w3, a8[j].w, m);
                acc += fmaxf(m, 0.f);
            }
        }
        for (; e < end; ++e) {
            int v0 = vb[e];
            float4 a0 = eap[e];
            float m0 = fmaf(w0, a0.x, YVs[v0 * 64 + lane]);
            m0 = fmaf(w1, a0.y, m0);
            m0 = fmaf(w2, a0.z, m0);
            m0 = fmaf(w3, a0.w, m0);
            acc += fmaxf(m0, 0.f);
        }

        int id = x_ids[n];
        float v = emb[(size_t)id * DD + lane] + acc;
        float au = biasu;
        #pragma unroll 8
        for (int k = 0; k < 64; ++k)
            au = fmaf(WuT[k * 64 + lane], lane_bcast(v, k), au);
        x1[(size_t)n * DD + lane] = fmaxf(au, 0.f);
    }
}

// ---------------------------------------------------------------------------
// Yb precompute (moved out of round1 for occupancy): Yb = x1 @ W2a.T + b2
// node-parallel, 4-node register blocking, 16 KB LDS -> high occupancy
// ---------------------------------------------------------------------------
__global__ __launch_bounds__(256) void yb_kernel(
    const float* __restrict__ x1, const float* __restrict__ Wn,
    const float* __restrict__ bn, float* __restrict__ Yb, int N)
{
    __shared__ float WnT[64 * 64];              // WnT[k*64+d] = Wn[d][k]
    for (int i = threadIdx.x; i < 64 * 64; i += 256) {
        int d = i & 63, k = i >> 6;
        WnT[i] = Wn[d * WCOLS + k];
    }
    __syncthreads();

    int lane = threadIdx.x & 63;
    int wid  = (blockIdx.x * 256 + threadIdx.x) >> 6;
    int nw   = (gridDim.x * 256) >> 6;
    float bias = bn[lane];

    for (int base = wid * 4; base < N; base += nw * 4) {
        int nvalid = N - base; if (nvalid > 4) nvalid = 4;
        float xv[4], acc[4];
        #pragma unroll
        for (int j = 0; j < 4; ++j) {
            xv[j] = (j < nvalid) ? x1[(size_t)(base + j) * DD + lane] : 0.f;
            acc[j] = bias;
        }
        #pragma unroll 8
        for (int k = 0; k < 64; ++k) {
            float w = WnT[k * 64 + lane];
            #pragma unroll
            for (int j = 0; j < 4; ++j)
                acc[j] = fmaf(w, lane_bcast(xv[j], k), acc[j]);
        }
        #pragma unroll
        for (int j = 0; j < 4; ++j)
            if (j < nvalid) Yb[(size_t)(base + j) * DD + lane] = acc[j];
    }
}

// ---------------------------------------------------------------------------
// round 2 (final): per dst node:
//   acc = sum_e relu(Yb[src(e)] + We2·ea(e))     (global gather, as r3)
//   o   = relu((x1 + acc) @ Wu2.T + bu2);  out_mean += o / N
// ---------------------------------------------------------------------------
__global__ __launch_bounds__(256) void round2_kernel(
    const int* __restrict__ rowp, const int* __restrict__ srcp,
    const float4* __restrict__ eap, const float* __restrict__ Y_in,
    const float* __restrict__ Wm,
    const float* __restrict__ Wu, const float* __restrict__ bu,
    const float* __restrict__ x1, float* __restrict__ out_mean,
    int N, float inv_n)
{
    __shared__ float WuT[64 * 64];
    __shared__ float red[256];
    for (int i = threadIdx.x; i < 64 * 64; i += 256) {
        int d = i & 63, k = i >> 6;
        WuT[i] = Wu[d * DD + k];
    }
    __syncthreads();

    int lane = threadIdx.x & 63;
    int wid  = __builtin_amdgcn_readfirstlane((blockIdx.x * 256 + (int)threadIdx.x) >> 6);
    int nw   = (gridDim.x * 256) >> 6;
    float w0 = Wm[lane * WCOLS + 64];
    float w1 = Wm[lane * WCOLS + 65];
    float w2 = Wm[lane * WCOLS + 66];
    float w3 = Wm[lane * WCOLS + 67];
    float biasu = bu[lane];
    float lsum = 0.f;

    for (int n = wid; n < N; n += nw) {
        int beg = rowp[n], end = rowp[n + 1];
        float acc = 0.f;
        int e = beg;
        for (; e + 3 < end; e += 4) {
            int s0 = srcp[e], s1 = srcp[e + 1], s2 = srcp[e + 2], s3 = srcp[e + 3];
            float4 a0 = eap[e], a1 = eap[e + 1], a2 = eap[e + 2], a3 = eap[e + 3];
            float y0 = Y_in[(size_t)s0 * DD + lane];
            float y1 = Y_in[(size_t)s1 * DD + lane];
            float y2 = Y_in[(size_t)s2 * DD + lane];
            float y3 = Y_in[(size_t)s3 * DD + lane];
            float m0 = y0 + w0 * a0.x + w1 * a0.y + w2 * a0.z + w3 * a0.w;
            float m1 = y1 + w0 * a1.x + w1 * a1.y + w2 * a1.z + w3 * a1.w;
            float m2 = y2 + w0 * a2.x + w1 * a2.y + w2 * a2.z + w3 * a2.w;
            float m3 = y3 + w0 * a3.x + w1 * a3.y + w2 * a3.z + w3 * a3.w;
            acc += fmaxf(m0, 0.f) + fmaxf(m1, 0.f) + fmaxf(m2, 0.f) + fmaxf(m3, 0.f);
        }
        for (; e < end; ++e) {
            int s0 = srcp[e];
            float4 a0 = eap[e];
            float y0 = Y_in[(size_t)s0 * DD + lane];
            float m0 = y0 + w0 * a0.x + w1 * a0.y + w2 * a0.z + w3 * a0.w;
            acc += fmaxf(m0, 0.f);
        }

        size_t o = (size_t)n * DD + lane;
        float v = x1[o] + acc;
        float au = biasu;
        #pragma unroll 8
        for (int k = 0; k < 64; ++k)
            au = fmaf(WuT[k * 64 + lane], lane_bcast(v, k), au);
        lsum += fmaxf(au, 0.f);
    }

    red[threadIdx.x] = lsum;
    __syncthreads();
    if (threadIdx.x < 64) {
        float s = red[threadIdx.x] + red[threadIdx.x + 64] +
                  red[threadIdx.x + 128] + red[threadIdx.x + 192];
        unsafeAtomicAdd(&out_mean[threadIdx.x], s * inv_n);
    }
}

// ---------------------------------------------------------------------------
extern "C" void kernel_launch(void* const* d_in, const int* in_sizes, int n_in,
                              void* d_out, int out_size, void* d_ws, size_t ws_size,
                              hipStream_t stream) {
    const int*   x_ids = (const int*)d_in[0];
    const int*   ei    = (const int*)d_in[1];
    const float* eattr = (const float*)d_in[2];
    const float* emb   = (const float*)d_in[3];
    const float* W1    = (const float*)d_in[4];
    const float* b1    = (const float*)d_in[5];
    const float* Wu1   = (const float*)d_in[6];
    const float* bu1   = (const float*)d_in[7];
    const float* W2    = (const float*)d_in[8];
    const float* b2    = (const float*)d_in[9];
    const float* Wu2   = (const float*)d_in[10];
    const float* bu2   = (const float*)d_in[11];

    const int N = in_sizes[0];
    const int E = in_sizes[1] / 2;
    const int* src = ei;
    const int* dst = ei + E;

    float* ws = (float*)d_ws;
    size_t stride = (size_t)N * DD;
    float*  x1   = ws;                              // N*64
    float*  Yb   = ws + stride;                     // N*64
    float*  eapf = ws + 2 * stride;                 // E*4 (16B-aligned)
    int*    srcp = (int*)(eapf + (size_t)E * 4);    // E
    int*    rowp = srcp + E;                        // N+1
    int*    deg  = rowp + N + 1;                    // N
    int*    cur  = deg + N;                         // N
    int*    bsum = cur + N;                         // 256
    float*  YV   = (float*)(bsum + 256);            // 100*64
    unsigned char* vb = (unsigned char*)(YV + VV * 64);  // E bytes
    float4* eap  = (float4*)eapf;

    float* out = (float*)d_out;
    float inv_n = 1.0f / (float)N;
    int nchunks = (N + 1023) / 1024;

    hipMemsetAsync(deg, 0, (size_t)N * sizeof(int), stream);
    hipMemsetAsync(out, 0, DD * sizeof(float), stream);

    // CSR build
    hist_kernel <<<2048, 256, 0, stream>>>(dst, deg, E);
    scan1_kernel<<<nchunks, 256, 0, stream>>>(deg, rowp, bsum, N);
    scan2_kernel<<<1, 256, 0, stream>>>(bsum, nchunks);
    scan3_kernel<<<(N + 255) / 256, 256, 0, stream>>>(rowp, bsum, cur, N, E);
    fill_kernel <<<2048, 256, 0, stream>>>(src, dst, x_ids, eattr, cur, srcp, vb, eap, E);

    // vocab table: YV = emb @ W1a.T + b1
    vocab_kernel<<<(VV + 3) / 4, 256, 0, stream>>>(emb, W1, b1, YV);

    // round 1 (LDS vocab table, no gather, no WnT) -> x1
    round1_kernel<<<2048, 256, 0, stream>>>(
        rowp, vb, eap, YV, x_ids, emb, W1, Wu1, bu1, x1, N);
    // Yb = x1 @ W2a.T + b2 (high-occupancy node-parallel)
    yb_kernel<<<1024, 256, 0, stream>>>(x1, W2, b2, Yb, N);
    // round 2 (gather Yb) -> out mean
    round2_kernel<<<2048, 256, 0, stream>>>(
        rowp, srcp, eap, Yb, W2, Wu2, bu2, x1, out, N, inv_n);
}

// Round 14
// 592.430 us; speedup vs baseline: 2.6091x; 1.0075x over previous
//
#include <hip/hip_runtime.h>

#define DD    64
#define WCOLS 68   // D + EF
#define VV    100  // vocab size

// one CSR edge record: single 64B-line scatter target (32B, line-aligned pairs)
struct alignas(32) Rec {
    float4 ea;      // edge_attr
    int    src;     // source node id
    int    voc;     // vocab id of source
    int    p0, p1;  // pad to 32B
};

__device__ __forceinline__ float lane_bcast(float v, int k) {
    return __int_as_float(__builtin_amdgcn_readlane(__float_as_int(v), k));
}

// ---------------------------------------------------------------------------
// CSR build: histogram of dst
// ---------------------------------------------------------------------------
__global__ __launch_bounds__(256) void hist_kernel(
    const int* __restrict__ dst, int* __restrict__ deg, int E)
{
    int i = blockIdx.x * 256 + threadIdx.x;
    int stride = gridDim.x * 256;
    for (; i < E; i += stride) atomicAdd(&deg[dst[i]], 1);
}

// scan phase 1: exclusive scan within 1024-element chunks (256 thr x 4 items)
__global__ __launch_bounds__(256) void scan1_kernel(
    const int* __restrict__ deg, int* __restrict__ rowp, int* __restrict__ bsum, int N)
{
    __shared__ int lds[256];
    int base = blockIdx.x * 1024;
    int t = threadIdx.x;
    int idx0 = base + t * 4;
    int v[4];
    #pragma unroll
    for (int j = 0; j < 4; ++j) v[j] = (idx0 + j < N) ? deg[idx0 + j] : 0;
    lds[t] = v[0] + v[1] + v[2] + v[3];
    __syncthreads();
    for (int off = 1; off < 256; off <<= 1) {
        int x = (t >= off) ? lds[t - off] : 0;
        __syncthreads();
        lds[t] += x;
        __syncthreads();
    }
    int run = (t > 0) ? lds[t - 1] : 0;
    if (t == 255) bsum[blockIdx.x] = lds[255];
    #pragma unroll
    for (int j = 0; j < 4; ++j) {
        if (idx0 + j < N) rowp[idx0 + j] = run;
        run += v[j];
    }
}

// scan phase 2: exclusive scan of chunk totals (nchunks <= 256)
__global__ __launch_bounds__(256) void scan2_kernel(int* __restrict__ bsum, int nchunks)
{
    __shared__ int lds[256];
    int t = threadIdx.x;
    int v = (t < nchunks) ? bsum[t] : 0;
    lds[t] = v;
    __syncthreads();
    for (int off = 1; off < 256; off <<= 1) {
        int x = (t >= off) ? lds[t - off] : 0;
        __syncthreads();
        lds[t] += x;
        __syncthreads();
    }
    if (t < nchunks) bsum[t] = (t > 0) ? lds[t - 1] : 0;
}

// scan phase 3: add chunk offsets; init cursor; rowp[N] = E
__global__ __launch_bounds__(256) void scan3_kernel(
    int* __restrict__ rowp, const int* __restrict__ bsum, int* __restrict__ cursor,
    int N, int E)
{
    int i = blockIdx.x * 256 + threadIdx.x;
    if (i == 0) rowp[N] = E;
    if (i < N) {
        int v = rowp[i] + bsum[i >> 10];
        rowp[i] = v;
        cursor[i] = v;
    }
}

// CSR fill: ONE 32B record per edge (single scattered line vs 3 before)
__global__ __launch_bounds__(256) void fill_kernel(
    const int* __restrict__ src, const int* __restrict__ dst,
    const int* __restrict__ x_ids, const float* __restrict__ eattr,
    int* __restrict__ cursor, Rec* __restrict__ rec, int E)
{
    int i = blockIdx.x * 256 + threadIdx.x;
    int stride = gridDim.x * 256;
    for (; i < E; i += stride) {
        int s = src[i];
        int d = dst[i];
        int pos = atomicAdd(&cursor[d], 1);
        Rec r;
        r.ea  = *(const float4*)(eattr + (size_t)i * 4);
        r.src = s;
        r.voc = x_ids[s];
        r.p0 = 0; r.p1 = 0;
        rec[pos] = r;
    }
}

// ---------------------------------------------------------------------------
// vocab precompute: YV[v] = emb[v] @ W1a.T + b1   (100 rows)
// ---------------------------------------------------------------------------
__global__ __launch_bounds__(256) void vocab_kernel(
    const float* __restrict__ emb, const float* __restrict__ W1,
    const float* __restrict__ b1, float* __restrict__ YV)
{
    __shared__ float WaT[64 * 64];              // WaT[k*64+d] = W1[d][k]
    for (int i = threadIdx.x; i < 64 * 64; i += 256) {
        int d = i & 63, k = i >> 6;
        WaT[i] = W1[d * WCOLS + k];
    }
    __syncthreads();

    int lane = threadIdx.x & 63;
    int wv = blockIdx.x * 4 + (threadIdx.x >> 6);
    if (wv >= VV) return;
    float xv = emb[wv * DD + lane];
    float acc = b1[lane];
    #pragma unroll 8
    for (int k = 0; k < 64; ++k)
        acc = fmaf(WaT[k * 64 + lane], lane_bcast(xv, k), acc);
    YV[wv * DD + lane] = acc;
}

// ---------------------------------------------------------------------------
// round 1 (fused, no global gather, no WnT): per dst node (one wave each):
//   acc = sum_e relu(YVs[rec.voc] + We1·rec.ea)    (LDS vocab table)
//   x1  = relu((emb[x_ids[n]] + acc) @ Wu1.T + bu1)
// LDS = YVs 25.6K + WuT 16K = 41.6 KB -> 3 blocks/CU
// ---------------------------------------------------------------------------
__global__ __launch_bounds__(256) void round1_kernel(
    const int* __restrict__ rowp, const Rec* __restrict__ rec,
    const float* __restrict__ YV,
    const int* __restrict__ x_ids, const float* __restrict__ emb,
    const float* __restrict__ W1,
    const float* __restrict__ Wu, const float* __restrict__ bu,
    float* __restrict__ x1, int N)
{
    __shared__ float YVs[VV * 64];              // 25.6 KB
    __shared__ float WuT[64 * 64];              // 16 KB  WuT[k*64+d]
    for (int i = threadIdx.x; i < VV * 64; i += 256) YVs[i] = YV[i];
    for (int i = threadIdx.x; i < 64 * 64; i += 256) {
        int d = i & 63, k = i >> 6;
        WuT[i] = Wu[d * DD + k];
    }
    __syncthreads();

    int lane = threadIdx.x & 63;
    int wid  = __builtin_amdgcn_readfirstlane((blockIdx.x * 256 + (int)threadIdx.x) >> 6);
    int nw   = (gridDim.x * 256) >> 6;
    float w0 = W1[lane * WCOLS + 64];
    float w1 = W1[lane * WCOLS + 65];
    float w2 = W1[lane * WCOLS + 66];
    float w3 = W1[lane * WCOLS + 67];
    float biasu = bu[lane];

    for (int n = wid; n < N; n += nw) {
        int beg = rowp[n], end = rowp[n + 1];
        float acc = 0.f;
        int e = beg;
        // 8-deep unroll: more independent record/LDS loads in flight
        for (; e + 7 < end; e += 8) {
            int   v8[8]; float4 a8[8];
            #pragma unroll
            for (int j = 0; j < 8; ++j) { v8[j] = rec[e + j].voc; a8[j] = rec[e + j].ea; }
            float y8[8];
            #pragma unroll
            for (int j = 0; j < 8; ++j) y8[j] = YVs[v8[j] * 64 + lane];
            #pragma unroll
            for (int j = 0; j < 8; ++j) {
                float m = fmaf(w0, a8[j].x, y8[j]);
                m = fmaf(w1, a8[j].y, m);
                m = fmaf(w2, a8[j].z, m);
                m = fmaf(w3, a8[j].w, m);
                acc += fmaxf(m, 0.f);
            }
        }
        for (; e < end; ++e) {
            int v0 = rec[e].voc;
            float4 a0 = rec[e].ea;
            float m0 = fmaf(w0, a0.x, YVs[v0 * 64 + lane]);
            m0 = fmaf(w1, a0.y, m0);
            m0 = fmaf(w2, a0.z, m0);
            m0 = fmaf(w3, a0.w, m0);
            acc += fmaxf(m0, 0.f);
        }

        int id = x_ids[n];
        float v = emb[(size_t)id * DD + lane] + acc;
        float au = biasu;
        #pragma unroll 8
        for (int k = 0; k < 64; ++k)
            au = fmaf(WuT[k * 64 + lane], lane_bcast(v, k), au);
        x1[(size_t)n * DD + lane] = fmaxf(au, 0.f);
    }
}

// ---------------------------------------------------------------------------
// Yb precompute: Yb = x1 @ W2a.T + b2 (high-occupancy node-parallel)
// ---------------------------------------------------------------------------
__global__ __launch_bounds__(256) void yb_kernel(
    const float* __restrict__ x1, const float* __restrict__ Wn,
    const float* __restrict__ bn, float* __restrict__ Yb, int N)
{
    __shared__ float WnT[64 * 64];              // WnT[k*64+d] = Wn[d][k]
    for (int i = threadIdx.x; i < 64 * 64; i += 256) {
        int d = i & 63, k = i >> 6;
        WnT[i] = Wn[d * WCOLS + k];
    }
    __syncthreads();

    int lane = threadIdx.x & 63;
    int wid  = (blockIdx.x * 256 + threadIdx.x) >> 6;
    int nw   = (gridDim.x * 256) >> 6;
    float bias = bn[lane];

    for (int base = wid * 4; base < N; base += nw * 4) {
        int nvalid = N - base; if (nvalid > 4) nvalid = 4;
        float xv[4], acc[4];
        #pragma unroll
        for (int j = 0; j < 4; ++j) {
            xv[j] = (j < nvalid) ? x1[(size_t)(base + j) * DD + lane] : 0.f;
            acc[j] = bias;
        }
        #pragma unroll 8
        for (int k = 0; k < 64; ++k) {
            float w = WnT[k * 64 + lane];
            #pragma unroll
            for (int j = 0; j < 4; ++j)
                acc[j] = fmaf(w, lane_bcast(xv[j], k), acc[j]);
        }
        #pragma unroll
        for (int j = 0; j < 4; ++j)
            if (j < nvalid) Yb[(size_t)(base + j) * DD + lane] = acc[j];
    }
}

// ---------------------------------------------------------------------------
// round 2 (final): per dst node:
//   acc = sum_e relu(Yb[rec.src] + We2·rec.ea)     (global gather)
//   o   = relu((x1 + acc) @ Wu2.T + bu2);  out_mean += o / N
// ---------------------------------------------------------------------------
__global__ __launch_bounds__(256) void round2_kernel(
    const int* __restrict__ rowp, const Rec* __restrict__ rec,
    const float* __restrict__ Y_in, const float* __restrict__ Wm,
    const float* __restrict__ Wu, const float* __restrict__ bu,
    const float* __restrict__ x1, float* __restrict__ out_mean,
    int N, float inv_n)
{
    __shared__ float WuT[64 * 64];
    __shared__ float red[256];
    for (int i = threadIdx.x; i < 64 * 64; i += 256) {
        int d = i & 63, k = i >> 6;
        WuT[i] = Wu[d * DD + k];
    }
    __syncthreads();

    int lane = threadIdx.x & 63;
    int wid  = __builtin_amdgcn_readfirstlane((blockIdx.x * 256 + (int)threadIdx.x) >> 6);
    int nw   = (gridDim.x * 256) >> 6;
    float w0 = Wm[lane * WCOLS + 64];
    float w1 = Wm[lane * WCOLS + 65];
    float w2 = Wm[lane * WCOLS + 66];
    float w3 = Wm[lane * WCOLS + 67];
    float biasu = bu[lane];
    float lsum = 0.f;

    for (int n = wid; n < N; n += nw) {
        int beg = rowp[n], end = rowp[n + 1];
        float acc = 0.f;
        int e = beg;
        for (; e + 3 < end; e += 4) {
            int s0 = rec[e].src, s1 = rec[e + 1].src, s2 = rec[e + 2].src, s3 = rec[e + 3].src;
            float4 a0 = rec[e].ea, a1 = rec[e + 1].ea, a2 = rec[e + 2].ea, a3 = rec[e + 3].ea;
            float y0 = Y_in[(size_t)s0 * DD + lane];
            float y1 = Y_in[(size_t)s1 * DD + lane];
            float y2 = Y_in[(size_t)s2 * DD + lane];
            float y3 = Y_in[(size_t)s3 * DD + lane];
            float m0 = y0 + w0 * a0.x + w1 * a0.y + w2 * a0.z + w3 * a0.w;
            float m1 = y1 + w0 * a1.x + w1 * a1.y + w2 * a1.z + w3 * a1.w;
            float m2 = y2 + w0 * a2.x + w1 * a2.y + w2 * a2.z + w3 * a2.w;
            float m3 = y3 + w0 * a3.x + w1 * a3.y + w2 * a3.z + w3 * a3.w;
            acc += fmaxf(m0, 0.f) + fmaxf(m1, 0.f) + fmaxf(m2, 0.f) + fmaxf(m3, 0.f);
        }
        for (; e < end; ++e) {
            int s0 = rec[e].src;
            float4 a0 = rec[e].ea;
            float y0 = Y_in[(size_t)s0 * DD + lane];
            float m0 = y0 + w0 * a0.x + w1 * a0.y + w2 * a0.z + w3 * a0.w;
            acc += fmaxf(m0, 0.f);
        }

        size_t o = (size_t)n * DD + lane;
        float v = x1[o] + acc;
        float au = biasu;
        #pragma unroll 8
        for (int k = 0; k < 64; ++k)
            au = fmaf(WuT[k * 64 + lane], lane_bcast(v, k), au);
        lsum += fmaxf(au, 0.f);
    }

    red[threadIdx.x] = lsum;
    __syncthreads();
    if (threadIdx.x < 64) {
        float s = red[threadIdx.x] + red[threadIdx.x + 64] +
                  red[threadIdx.x + 128] + red[threadIdx.x + 192];
        unsafeAtomicAdd(&out_mean[threadIdx.x], s * inv_n);
    }
}

// ---------------------------------------------------------------------------
extern "C" void kernel_launch(void* const* d_in, const int* in_sizes, int n_in,
                              void* d_out, int out_size, void* d_ws, size_t ws_size,
                              hipStream_t stream) {
    const int*   x_ids = (const int*)d_in[0];
    const int*   ei    = (const int*)d_in[1];
    const float* eattr = (const float*)d_in[2];
    const float* emb   = (const float*)d_in[3];
    const float* W1    = (const float*)d_in[4];
    const float* b1    = (const float*)d_in[5];
    const float* Wu1   = (const float*)d_in[6];
    const float* bu1   = (const float*)d_in[7];
    const float* W2    = (const float*)d_in[8];
    const float* b2    = (const float*)d_in[9];
    const float* Wu2   = (const float*)d_in[10];
    const float* bu2   = (const float*)d_in[11];

    const int N = in_sizes[0];
    const int E = in_sizes[1] / 2;
    const int* src = ei;
    const int* dst = ei + E;

    float* ws = (float*)d_ws;
    size_t stride = (size_t)N * DD;
    float*  x1   = ws;                              // N*64 f32
    float*  Yb   = ws + stride;                     // N*64 f32
    Rec*    rec  = (Rec*)(ws + 2 * stride);         // E*32B (offset mult of 32B)
    int*    rowp = (int*)(rec + E);                 // N+1
    int*    deg  = rowp + N + 1;                    // N
    int*    cur  = deg + N;                         // N
    int*    bsum = cur + N;                         // 256
    float*  YV   = (float*)(bsum + 256);            // 100*64

    float* out = (float*)d_out;
    float inv_n = 1.0f / (float)N;
    int nchunks = (N + 1023) / 1024;

    hipMemsetAsync(deg, 0, (size_t)N * sizeof(int), stream);
    hipMemsetAsync(out, 0, DD * sizeof(float), stream);

    // CSR build
    hist_kernel <<<2048, 256, 0, stream>>>(dst, deg, E);
    scan1_kernel<<<nchunks, 256, 0, stream>>>(deg, rowp, bsum, N);
    scan2_kernel<<<1, 256, 0, stream>>>(bsum, nchunks);
    scan3_kernel<<<(N + 255) / 256, 256, 0, stream>>>(rowp, bsum, cur, N, E);
    fill_kernel <<<2048, 256, 0, stream>>>(src, dst, x_ids, eattr, cur, rec, E);

    // vocab table: YV = emb @ W1a.T + b1
    vocab_kernel<<<(VV + 3) / 4, 256, 0, stream>>>(emb, W1, b1, YV);

    // round 1 (LDS vocab table, no gather, no WnT) -> x1
    round1_kernel<<<2048, 256, 0, stream>>>(
        rowp, rec, YV, x_ids, emb, W1, Wu1, bu1, x1, N);
    // Yb = x1 @ W2a.T + b2 (high-occupancy node-parallel)
    yb_kernel<<<1024, 256, 0, stream>>>(x1, W2, b2, Yb, N);
    // round 2 (gather Yb) -> out mean
    round2_kernel<<<2048, 256, 0, stream>>>(
        rowp, rec, Yb, W2, Wu2, bu2, x1, out, N, inv_n);
}

// Round 15
// 562.825 us; speedup vs baseline: 2.7463x; 1.0526x over previous
//
#include <hip/hip_runtime.h>

#define DD    64
#define WCOLS 68   // D + EF
#define VV    100  // vocab size

// one CSR edge record: single 64B-line scatter target
struct alignas(32) Rec {
    float4 ea;      // edge_attr
    int    src;     // source node id
    int    voc;     // vocab id of source
    int    p0, p1;  // pad to 32B
};

__device__ __forceinline__ float lane_bcast(float v, int k) {
    return __int_as_float(__builtin_amdgcn_readlane(__float_as_int(v), k));
}

// ---------------------------------------------------------------------------
// CSR build: histogram of dst
// ---------------------------------------------------------------------------
__global__ __launch_bounds__(256) void hist_kernel(
    const int* __restrict__ dst, int* __restrict__ deg, int E)
{
    int i = blockIdx.x * 256 + threadIdx.x;
    int stride = gridDim.x * 256;
    for (; i < E; i += stride) atomicAdd(&deg[dst[i]], 1);
}

// scan phase 1: exclusive scan within 1024-element chunks (256 thr x 4 items)
__global__ __launch_bounds__(256) void scan1_kernel(
    const int* __restrict__ deg, int* __restrict__ rowp, int* __restrict__ bsum, int N)
{
    __shared__ int lds[256];
    int base = blockIdx.x * 1024;
    int t = threadIdx.x;
    int idx0 = base + t * 4;
    int v[4];
    #pragma unroll
    for (int j = 0; j < 4; ++j) v[j] = (idx0 + j < N) ? deg[idx0 + j] : 0;
    lds[t] = v[0] + v[1] + v[2] + v[3];
    __syncthreads();
    for (int off = 1; off < 256; off <<= 1) {
        int x = (t >= off) ? lds[t - off] : 0;
        __syncthreads();
        lds[t] += x;
        __syncthreads();
    }
    int run = (t > 0) ? lds[t - 1] : 0;
    if (t == 255) bsum[blockIdx.x] = lds[255];
    #pragma unroll
    for (int j = 0; j < 4; ++j) {
        if (idx0 + j < N) rowp[idx0 + j] = run;
        run += v[j];
    }
}

// scan phase 2: exclusive scan of chunk totals (nchunks <= 256)
__global__ __launch_bounds__(256) void scan2_kernel(int* __restrict__ bsum, int nchunks)
{
    __shared__ int lds[256];
    int t = threadIdx.x;
    int v = (t < nchunks) ? bsum[t] : 0;
    lds[t] = v;
    __syncthreads();
    for (int off = 1; off < 256; off <<= 1) {
        int x = (t >= off) ? lds[t - off] : 0;
        __syncthreads();
        lds[t] += x;
        __syncthreads();
    }
    if (t < nchunks) bsum[t] = (t > 0) ? lds[t - 1] : 0;
}

// scan phase 3: add chunk offsets; init cursor; rowp[N] = E
__global__ __launch_bounds__(256) void scan3_kernel(
    int* __restrict__ rowp, const int* __restrict__ bsum, int* __restrict__ cursor,
    int N, int E)
{
    int i = blockIdx.x * 256 + threadIdx.x;
    if (i == 0) rowp[N] = E;
    if (i < N) {
        int v = rowp[i] + bsum[i >> 10];
        rowp[i] = v;
        cursor[i] = v;
    }
}

// CSR fill: ONE 32B record per edge (single scattered line)
__global__ __launch_bounds__(256) void fill_kernel(
    const int* __restrict__ src, const int* __restrict__ dst,
    const int* __restrict__ x_ids, const float* __restrict__ eattr,
    int* __restrict__ cursor, Rec* __restrict__ rec, int E)
{
    int i = blockIdx.x * 256 + threadIdx.x;
    int stride = gridDim.x * 256;
    for (; i < E; i += stride) {
        int s = src[i];
        int d = dst[i];
        int pos = atomicAdd(&cursor[d], 1);
        Rec r;
        r.ea  = *(const float4*)(eattr + (size_t)i * 4);
        r.src = s;
        r.voc = x_ids[s];
        r.p0 = 0; r.p1 = 0;
        rec[pos] = r;
    }
}

// ---------------------------------------------------------------------------
// vocab precompute: YV[v] = emb[v] @ W1a.T + b1   (100 rows)
// ---------------------------------------------------------------------------
__global__ __launch_bounds__(256) void vocab_kernel(
    const float* __restrict__ emb, const float* __restrict__ W1,
    const float* __restrict__ b1, float* __restrict__ YV)
{
    __shared__ float WaT[64 * 64];              // WaT[k*64+d] = W1[d][k]
    for (int i = threadIdx.x; i < 64 * 64; i += 256) {
        int d = i & 63, k = i >> 6;
        WaT[i] = W1[d * WCOLS + k];
    }
    __syncthreads();

    int lane = threadIdx.x & 63;
    int wv = blockIdx.x * 4 + (threadIdx.x >> 6);
    if (wv >= VV) return;
    float xv = emb[wv * DD + lane];
    float acc = b1[lane];
    #pragma unroll 8
    for (int k = 0; k < 64; ++k)
        acc = fmaf(WaT[k * 64 + lane], lane_bcast(xv, k), acc);
    YV[wv * DD + lane] = acc;
}

// ---------------------------------------------------------------------------
// round-1 EDGE-ONLY kernel: per dst node (one wave each):
//   agg[n] = sum_e relu(YVs[rec.voc] + We1·rec.ea)
// LDS = YVs only (25.6 KB) -> up to 6 blocks/CU (~75% occupancy)
// ---------------------------------------------------------------------------
__global__ __launch_bounds__(256) void edge_r1_kernel(
    const int* __restrict__ rowp, const Rec* __restrict__ rec,
    const float* __restrict__ YV, const float* __restrict__ W1,
    float* __restrict__ agg, int N)
{
    __shared__ float YVs[VV * 64];              // 25.6 KB only
    for (int i = threadIdx.x; i < VV * 64; i += 256) YVs[i] = YV[i];
    __syncthreads();

    int lane = threadIdx.x & 63;
    int wid  = __builtin_amdgcn_readfirstlane((blockIdx.x * 256 + (int)threadIdx.x) >> 6);
    int nw   = (gridDim.x * 256) >> 6;
    float w0 = W1[lane * WCOLS + 64];
    float w1 = W1[lane * WCOLS + 65];
    float w2 = W1[lane * WCOLS + 66];
    float w3 = W1[lane * WCOLS + 67];

    for (int n = wid; n < N; n += nw) {
        int beg = rowp[n], end = rowp[n + 1];
        float acc = 0.f;
        int e = beg;
        for (; e + 7 < end; e += 8) {
            int   v8[8]; float4 a8[8];
            #pragma unroll
            for (int j = 0; j < 8; ++j) { v8[j] = rec[e + j].voc; a8[j] = rec[e + j].ea; }
            float y8[8];
            #pragma unroll
            for (int j = 0; j < 8; ++j) y8[j] = YVs[v8[j] * 64 + lane];
            #pragma unroll
            for (int j = 0; j < 8; ++j) {
                float m = fmaf(w0, a8[j].x, y8[j]);
                m = fmaf(w1, a8[j].y, m);
                m = fmaf(w2, a8[j].z, m);
                m = fmaf(w3, a8[j].w, m);
                acc += fmaxf(m, 0.f);
            }
        }
        for (; e < end; ++e) {
            int v0 = rec[e].voc;
            float4 a0 = rec[e].ea;
            float m0 = fmaf(w0, a0.x, YVs[v0 * 64 + lane]);
            m0 = fmaf(w1, a0.y, m0);
            m0 = fmaf(w2, a0.z, m0);
            m0 = fmaf(w3, a0.w, m0);
            acc += fmaxf(m0, 0.f);
        }
        agg[(size_t)n * DD + lane] = acc;
    }
}

// ---------------------------------------------------------------------------
// round-1 NODE kernel (replaces round1 tail + yb_kernel):
//   x1 = relu((emb[x_ids] + agg) @ Wu1.T + bu1)   (agg read IN PLACE from x1 buf)
//   Yb = x1 @ W2a.T + b2
// 4-node register blocking, 32 KB LDS -> high occupancy
// ---------------------------------------------------------------------------
__global__ __launch_bounds__(256) void node1_kernel(
    const int* __restrict__ x_ids, const float* __restrict__ emb,
    const float* __restrict__ Wu, const float* __restrict__ bu,
    const float* __restrict__ Wn, const float* __restrict__ bn,
    float* __restrict__ x1 /* = agg in */, float* __restrict__ Yb, int N)
{
    __shared__ float WuT[64 * 64];              // WuT[k*64+d] = Wu[d][k]
    __shared__ float WnT[64 * 64];              // WnT[k*64+d] = Wn[d][k]
    for (int i = threadIdx.x; i < 64 * 64; i += 256) {
        int d = i & 63, k = i >> 6;
        WuT[i] = Wu[d * DD + k];
        WnT[i] = Wn[d * WCOLS + k];
    }
    __syncthreads();

    int lane = threadIdx.x & 63;
    int wid  = (blockIdx.x * 256 + threadIdx.x) >> 6;
    int nw   = (gridDim.x * 256) >> 6;
    float biasu = bu[lane];
    float biasn = bn[lane];

    for (int base = wid * 4; base < N; base += nw * 4) {
        int nvalid = N - base; if (nvalid > 4) nvalid = 4;
        float v[4], acc[4];
        #pragma unroll
        for (int j = 0; j < 4; ++j) {
            if (j < nvalid) {
                size_t o = (size_t)(base + j) * DD + lane;
                v[j] = emb[(size_t)x_ids[base + j] * DD + lane] + x1[o];
            } else v[j] = 0.f;
            acc[j] = biasu;
        }
        #pragma unroll 8
        for (int k = 0; k < 64; ++k) {
            float w = WuT[k * 64 + lane];
            #pragma unroll
            for (int j = 0; j < 4; ++j)
                acc[j] = fmaf(w, lane_bcast(v[j], k), acc[j]);
        }
        float o4[4];
        #pragma unroll
        for (int j = 0; j < 4; ++j) o4[j] = fmaxf(acc[j], 0.f);

        float acc2[4];
        #pragma unroll
        for (int j = 0; j < 4; ++j) acc2[j] = biasn;
        #pragma unroll 8
        for (int k = 0; k < 64; ++k) {
            float w = WnT[k * 64 + lane];
            #pragma unroll
            for (int j = 0; j < 4; ++j)
                acc2[j] = fmaf(w, lane_bcast(o4[j], k), acc2[j]);
        }
        #pragma unroll
        for (int j = 0; j < 4; ++j) {
            if (j < nvalid) {
                size_t o = (size_t)(base + j) * DD + lane;
                x1[o] = o4[j];
                Yb[o] = acc2[j];
            }
        }
    }
}

// ---------------------------------------------------------------------------
// round 2 (final): per dst node:
//   acc = sum_e relu(Yb[rec.src] + We2·rec.ea)     (global gather)
//   o   = relu((x1 + acc) @ Wu2.T + bu2);  out_mean += o / N
// ---------------------------------------------------------------------------
__global__ __launch_bounds__(256) void round2_kernel(
    const int* __restrict__ rowp, const Rec* __restrict__ rec,
    const float* __restrict__ Y_in, const float* __restrict__ Wm,
    const float* __restrict__ Wu, const float* __restrict__ bu,
    const float* __restrict__ x1, float* __restrict__ out_mean,
    int N, float inv_n)
{
    __shared__ float WuT[64 * 64];
    __shared__ float red[256];
    for (int i = threadIdx.x; i < 64 * 64; i += 256) {
        int d = i & 63, k = i >> 6;
        WuT[i] = Wu[d * DD + k];
    }
    __syncthreads();

    int lane = threadIdx.x & 63;
    int wid  = __builtin_amdgcn_readfirstlane((blockIdx.x * 256 + (int)threadIdx.x) >> 6);
    int nw   = (gridDim.x * 256) >> 6;
    float w0 = Wm[lane * WCOLS + 64];
    float w1 = Wm[lane * WCOLS + 65];
    float w2 = Wm[lane * WCOLS + 66];
    float w3 = Wm[lane * WCOLS + 67];
    float biasu = bu[lane];
    float lsum = 0.f;

    for (int n = wid; n < N; n += nw) {
        int beg = rowp[n], end = rowp[n + 1];
        float acc = 0.f;
        int e = beg;
        for (; e + 3 < end; e += 4) {
            int s0 = rec[e].src, s1 = rec[e + 1].src, s2 = rec[e + 2].src, s3 = rec[e + 3].src;
            float4 a0 = rec[e].ea, a1 = rec[e + 1].ea, a2 = rec[e + 2].ea, a3 = rec[e + 3].ea;
            float y0 = Y_in[(size_t)s0 * DD + lane];
            float y1 = Y_in[(size_t)s1 * DD + lane];
            float y2 = Y_in[(size_t)s2 * DD + lane];
            float y3 = Y_in[(size_t)s3 * DD + lane];
            float m0 = y0 + w0 * a0.x + w1 * a0.y + w2 * a0.z + w3 * a0.w;
            float m1 = y1 + w0 * a1.x + w1 * a1.y + w2 * a1.z + w3 * a1.w;
            float m2 = y2 + w0 * a2.x + w1 * a2.y + w2 * a2.z + w3 * a2.w;
            float m3 = y3 + w0 * a3.x + w1 * a3.y + w2 * a3.z + w3 * a3.w;
            acc += fmaxf(m0, 0.f) + fmaxf(m1, 0.f) + fmaxf(m2, 0.f) + fmaxf(m3, 0.f);
        }
        for (; e < end; ++e) {
            int s0 = rec[e].src;
            float4 a0 = rec[e].ea;
            float y0 = Y_in[(size_t)s0 * DD + lane];
            float m0 = y0 + w0 * a0.x + w1 * a0.y + w2 * a0.z + w3 * a0.w;
            acc += fmaxf(m0, 0.f);
        }

        size_t o = (size_t)n * DD + lane;
        float v = x1[o] + acc;
        float au = biasu;
        #pragma unroll 8
        for (int k = 0; k < 64; ++k)
            au = fmaf(WuT[k * 64 + lane], lane_bcast(v, k), au);
        lsum += fmaxf(au, 0.f);
    }

    red[threadIdx.x] = lsum;
    __syncthreads();
    if (threadIdx.x < 64) {
        float s = red[threadIdx.x] + red[threadIdx.x + 64] +
                  red[threadIdx.x + 128] + red[threadIdx.x + 192];
        unsafeAtomicAdd(&out_mean[threadIdx.x], s * inv_n);
    }
}

// ---------------------------------------------------------------------------
extern "C" void kernel_launch(void* const* d_in, const int* in_sizes, int n_in,
                              void* d_out, int out_size, void* d_ws, size_t ws_size,
                              hipStream_t stream) {
    const int*   x_ids = (const int*)d_in[0];
    const int*   ei    = (const int*)d_in[1];
    const float* eattr = (const float*)d_in[2];
    const float* emb   = (const float*)d_in[3];
    const float* W1    = (const float*)d_in[4];
    const float* b1    = (const float*)d_in[5];
    const float* Wu1   = (const float*)d_in[6];
    const float* bu1   = (const float*)d_in[7];
    const float* W2    = (const float*)d_in[8];
    const float* b2    = (const float*)d_in[9];
    const float* Wu2   = (const float*)d_in[10];
    const float* bu2   = (const float*)d_in[11];

    const int N = in_sizes[0];
    const int E = in_sizes[1] / 2;
    const int* src = ei;
    const int* dst = ei + E;

    float* ws = (float*)d_ws;
    size_t stride = (size_t)N * DD;
    float*  x1   = ws;                              // N*64 f32 (= agg in round 1)
    float*  Yb   = ws + stride;                     // N*64 f32
    Rec*    rec  = (Rec*)(ws + 2 * stride);         // E*32B
    int*    rowp = (int*)(rec + E);                 // N+1
    int*    deg  = rowp + N + 1;                    // N
    int*    cur  = deg + N;                         // N
    int*    bsum = cur + N;                         // 256
    float*  YV   = (float*)(bsum + 256);            // 100*64

    float* out = (float*)d_out;
    float inv_n = 1.0f / (float)N;
    int nchunks = (N + 1023) / 1024;

    hipMemsetAsync(deg, 0, (size_t)N * sizeof(int), stream);
    hipMemsetAsync(out, 0, DD * sizeof(float), stream);

    // CSR build
    hist_kernel <<<2048, 256, 0, stream>>>(dst, deg, E);
    scan1_kernel<<<nchunks, 256, 0, stream>>>(deg, rowp, bsum, N);
    scan2_kernel<<<1, 256, 0, stream>>>(bsum, nchunks);
    scan3_kernel<<<(N + 255) / 256, 256, 0, stream>>>(rowp, bsum, cur, N, E);
    fill_kernel <<<2048, 256, 0, stream>>>(src, dst, x_ids, eattr, cur, rec, E);

    // vocab table: YV = emb @ W1a.T + b1
    vocab_kernel<<<(VV + 3) / 4, 256, 0, stream>>>(emb, W1, b1, YV);

    // round 1: edge-only aggregation (high occupancy) -> agg (in x1 buffer)
    edge_r1_kernel<<<2048, 256, 0, stream>>>(rowp, rec, YV, W1, x1, N);
    // round 1 node phase + Yb precompute (two matvecs, in-place agg->x1)
    node1_kernel<<<1024, 256, 0, stream>>>(x_ids, emb, Wu1, bu1, W2, b2, x1, Yb, N);
    // round 2 (gather Yb) -> out mean
    round2_kernel<<<2048, 256, 0, stream>>>(
        rowp, rec, Yb, W2, Wu2, bu2, x1, out, N, inv_n);
}